// Round 10
// baseline (175.085 us; speedup 1.0000x reference)
//
#include <hip/hip_runtime.h>
#include <hip/hip_bf16.h>

#define BATCH 4
#define CCH   256
#define HH    128
#define WW    128
#define HWSZ  (HH * WW)         // 16384
#define NHEADS 4
#define DHEAD 64
#define KDIM  256
#define PDIM  16384

typedef unsigned short u16;
typedef short bf16x8 __attribute__((ext_vector_type(8)));
typedef float f32x4  __attribute__((ext_vector_type(4)));

__device__ __forceinline__ float bf2f(u16 u) {
    return __uint_as_float(((unsigned)u) << 16);
}
__device__ __forceinline__ u16 f2bf(float f) {
    unsigned u = __float_as_uint(f);
    unsigned r = (u + 0x7fffu + ((u >> 16) & 1u)) >> 16;
    return (u16)r;
}
__device__ __forceinline__ unsigned pack2(float a, float b) {
    return (unsigned)f2bf(a) | ((unsigned)f2bf(b) << 16);
}
__device__ __forceinline__ void gl_lds16(const u16* g, u16* l) {
    __builtin_amdgcn_global_load_lds(
        (const __attribute__((address_space(1))) void*)g,
        (__attribute__((address_space(3))) void*)l, 16, 0, 0);
}

// ---------------------------------------------------------------------------
// Weight fp32 -> bf16 conversion (both weights in one kernel).
// ---------------------------------------------------------------------------
__global__ __launch_bounds__(256) void wconv(
    const float* __restrict__ wq, const float* __restrict__ wp,
    u16* __restrict__ wqb, u16* __restrict__ wpb)
{
    const int i = (blockIdx.x * 256 + threadIdx.x) * 4;   // < 262144
    const float4 v = (i < 196608)
        ? *reinterpret_cast<const float4*>(&wq[i])
        : *reinterpret_cast<const float4*>(&wp[i - 196608]);
    ushort4 o;
    o.x = f2bf(v.x); o.y = f2bf(v.y); o.z = f2bf(v.z); o.w = f2bf(v.w);
    if (i < 196608) *reinterpret_cast<ushort4*>(&wqb[i]) = o;
    else            *reinterpret_cast<ushort4*>(&wpb[i - 196608]) = o;
}

// ---------------------------------------------------------------------------
// Transpose + convert: x [b][c][p] fp32 -> XT [b][p][c] bf16. 32x32 tiles.
// ---------------------------------------------------------------------------
__global__ __launch_bounds__(256) void transpose_x(
    const float* __restrict__ x, u16* __restrict__ XT)
{
    __shared__ float t[32][33];
    const int b  = blockIdx.z;
    const int c0 = blockIdx.y * 32;
    const int p0 = blockIdx.x * 32;
    const int tid = threadIdx.x;

    #pragma unroll
    for (int it = 0; it < 4; ++it) {
        const int r = it * 8 + (tid >> 5);
        const int col = tid & 31;
        t[r][col] = x[((size_t)b * CCH + c0 + r) * HWSZ + p0 + col];
    }
    __syncthreads();
    #pragma unroll
    for (int it = 0; it < 2; ++it) {
        const int prow = it * 16 + (tid >> 4);
        const int cpair = (tid & 15) * 2;
        const float v0 = t[cpair][prow];
        const float v1 = t[cpair + 1][prow];
        ushort2 o; o.x = f2bf(v0); o.y = f2bf(v1);
        *reinterpret_cast<ushort2*>(
            &XT[((size_t)b * HWSZ + p0 + prow) * CCH + c0 + cpair]) = o;
    }
}

// ---------------------------------------------------------------------------
// QKV MFMA GEMM: D[o][p] = sum_k WQ[o][k] * XT[p][k]  (bf16, k-contiguous)
// K=256, BK=64, tile 128x128, 4 waves (2x2), mfma_f32_16x16x32_bf16.
// Epilogue: C-tile -> LDS Ct[2][128][72] (pixel-major, 144B rows) ->
// coalesced 16B stores into QKVH [(z*4+head)][p][q64|k64|v64].
// Store decomposition: c(8 chunks) x sl(2) x px0(16) x 8 passes = full tile.
// ---------------------------------------------------------------------------
__global__ __launch_bounds__(256) void gemm_qkv(
    const u16* __restrict__ A, const u16* __restrict__ B,
    u16* __restrict__ QKVH, long long b_zs)
{
    constexpr int BK = 64;
    constexpr int CTP = 72;               // Ct row stride (u16): 144B, 16B mult
    __shared__ __align__(16) u16 lds[18432];  // 36864 B union
    u16* As = lds;                        // 8192 u16
    u16* Bs = lds + 8192;                 // 8192 u16

    const int tid  = threadIdx.x;
    const int lane = tid & 63;
    const int w    = tid >> 6;
    const int wm   = w >> 1, wn = w & 1;
    const int o0   = blockIdx.y * 128;
    const int p0   = blockIdx.x * 128;
    const int z    = blockIdx.z;
    const u16* Bz  = B + (size_t)z * b_zs;

    const int srow  = lane >> 3;
    const int sslot = (lane & 7) ^ srow;

    auto stage = [&](int c0) {
        #pragma unroll
        for (int j = 0; j < 4; ++j) {
            const int q = w * 4 + j;
            const int r = q * 8 + srow;
            gl_lds16(A  + (size_t)(o0 + r) * KDIM + c0 + sslot * 8, As + q * 512);
            gl_lds16(Bz + (size_t)(p0 + r) * KDIM + c0 + sslot * 8, Bs + q * 512);
        }
    };

    f32x4 acc[4][4];
    #pragma unroll
    for (int m = 0; m < 4; ++m)
        #pragma unroll
        for (int n = 0; n < 4; ++n)
            acc[m][n] = (f32x4){0.f, 0.f, 0.f, 0.f};

    stage(0);
    #pragma unroll
    for (int kt = 0; kt < KDIM / BK; ++kt) {
        __syncthreads();
        #pragma unroll
        for (int h = 0; h < 2; ++h) {
            bf16x8 af[4], bfr[4];
            #pragma unroll
            for (int m = 0; m < 4; ++m) {
                const int r  = wm * 64 + m * 16 + (lane & 15);
                const int sl = ((h << 2) | (lane >> 4)) ^ (r & 7);
                af[m] = *reinterpret_cast<const bf16x8*>(As + r * BK + sl * 8);
            }
            #pragma unroll
            for (int n = 0; n < 4; ++n) {
                const int r  = wn * 64 + n * 16 + (lane & 15);
                const int sl = ((h << 2) | (lane >> 4)) ^ (r & 7);
                bfr[n] = *reinterpret_cast<const bf16x8*>(Bs + r * BK + sl * 8);
            }
            #pragma unroll
            for (int m = 0; m < 4; ++m)
                #pragma unroll
                for (int n = 0; n < 4; ++n)
                    acc[m][n] = __builtin_amdgcn_mfma_f32_16x16x32_bf16(
                        af[m], bfr[n], acc[m][n], 0, 0, 0);
        }
        if (kt + 1 < KDIM / BK) {
            __syncthreads();
            stage((kt + 1) * BK);
        }
    }

    // Epilogue: acc -> LDS Ct[2][128][CTP] u16 (slice = wm), pixel-major.
    __syncthreads();                      // all LDS reads done, safe to reuse
    u16* Ct = lds;                        // 2*128*72*2 = 36864 B
    const int g = lane >> 4, ln15 = lane & 15;
    #pragma unroll
    for (int m = 0; m < 4; ++m) {
        const int och = m * 16 + g * 4;   // within-slice channel (j packed)
        #pragma unroll
        for (int n = 0; n < 4; ++n) {
            const int px = wn * 64 + n * 16 + ln15;
            uint2 w2;
            w2.x = pack2(acc[m][n][0], acc[m][n][1]);
            w2.y = pack2(acc[m][n][2], acc[m][n][3]);
            *reinterpret_cast<uint2*>(&Ct[(wm * 128 + px) * CTP + och]) = w2;
        }
    }
    __syncthreads();

    // Coalesced store: full coverage 2 slices x 128 px x 8 chunks.
    const int c   = tid & 7;              // 16B chunk within 64-ch slice
    const int sl  = (tid >> 3) & 1;       // slice (o0 + sl*64)
    const int px0 = tid >> 4;             // 0..15
    const int abs_slice = blockIdx.y * 2 + sl;   // 0..11
    const int qkv  = abs_slice >> 2;
    const int head = abs_slice & 3;
    u16* dbase = QKVH + ((size_t)(z * NHEADS + head) * HWSZ) * 192 + qkv * 64 + c * 8;
    #pragma unroll
    for (int pass = 0; pass < 8; ++pass) {
        const int px = px0 + pass * 16;
        const uint4 val = *reinterpret_cast<const uint4*>(
            &Ct[(sl * 128 + px) * CTP + c * 8]);
        *reinterpret_cast<uint4*>(dbase + (size_t)(p0 + px) * 192) = val;
    }
}

// ---------------------------------------------------------------------------
// Fused attention + proj GEMM + BN partials.
// Block: 32 px, 256 thr. Attention: ONE HEAD PER WAVE (head = tid>>6),
// 2 thr/px x 32 ch, pair-combined via shfl_xor(1); all 4 heads concurrent.
// y (32px x 256ch bf16) staged in LDS. Proj: 4 waves x (64 out x 32 px) MFMA,
// A-frags (W_proj) from global/L2, B-frags from LDS. Writes YP bf16 [b][o][p]
// and per-(channel, 32px-block) (sum,sumsq) partials.
// ---------------------------------------------------------------------------
__global__ __launch_bounds__(256) void attn_proj(
    const u16* __restrict__ QKVH, const u16* __restrict__ WP,
    u16* __restrict__ YP, float* __restrict__ part, int batch0)
{
    __shared__ u16 y_lds[32][264];        // 16.9 KB, rows padded (+8)
    const int tid = threadIdx.x;
    const int z   = blockIdx.z;
    const int batch = batch0 + z;
    const int bxr = blockIdx.x;                     // 0..511
    const int bx  = (bxr & 7) * 64 + (bxr >> 3);    // XCD-contiguous bands
    const int lane = tid & 63;
    const int w    = tid >> 6;

    // ---- Attention phase: wave w handles head w; 2 threads/px, 32 ch each.
    {
        const int hi   = w;
        const int pxl  = lane >> 1;                 // 0..31
        const int half = lane & 1;                  // 32-ch half
        const int p    = bx * 32 + pxl;
        const int yy = p >> 7, xx = p & 127;
        const int r  = hi + 1;
        const u16* base = QKVH + ((size_t)(z * NHEADS + hi) * HWSZ) * 192;

        // q: 32 channels
        const uint4* qp = reinterpret_cast<const uint4*>(
            base + (size_t)p * 192 + half * 32);
        float qf[32];
        #pragma unroll
        for (int c4 = 0; c4 < 4; ++c4) {
            const uint4 t = qp[c4];
            const unsigned wv[4] = {t.x, t.y, t.z, t.w};
            #pragma unroll
            for (int d = 0; d < 4; ++d) {
                qf[c4 * 8 + d * 2 + 0] = __uint_as_float(wv[d] << 16);
                qf[c4 * 8 + d * 2 + 1] = __uint_as_float(wv[d] & 0xffff0000u);
            }
        }

        int offs[9]; float valid[9];
        #pragma unroll
        for (int n = 0; n < 9; ++n) {
            const int dy = (n / 3 - 1) * r;
            const int dx = (n % 3 - 1) * r;
            const int y2 = yy + dy, x2 = xx + dx;
            const bool ok = (y2 >= 0) && (y2 < HH) && (x2 >= 0) && (x2 < WW);
            valid[n] = ok ? 1.f : 0.f;
            const int y2c = min(max(y2, 0), HH - 1);
            const int x2c = min(max(x2, 0), WW - 1);
            offs[n] = y2c * WW + x2c;
        }

        float sc[9];
        #pragma unroll
        for (int n = 0; n < 9; ++n) {
            const uint4* kp = reinterpret_cast<const uint4*>(
                base + (size_t)offs[n] * 192 + 64 + half * 32);
            float s = 0.f;
            #pragma unroll
            for (int c4 = 0; c4 < 4; ++c4) {
                const uint4 t = kp[c4];
                const unsigned wv[4] = {t.x, t.y, t.z, t.w};
                #pragma unroll
                for (int d = 0; d < 4; ++d) {
                    s += qf[c4 * 8 + d * 2 + 0] * __uint_as_float(wv[d] << 16);
                    s += qf[c4 * 8 + d * 2 + 1] * __uint_as_float(wv[d] & 0xffff0000u);
                }
            }
            sc[n] = s;
        }
        #pragma unroll
        for (int n = 0; n < 9; ++n) {
            sc[n] += __shfl_xor(sc[n], 1);
            sc[n] *= valid[n];            // OOB -> exactly 0 (in softmax)
        }

        float m = sc[0];
        #pragma unroll
        for (int n = 1; n < 9; ++n) m = fmaxf(m, sc[n]);
        float wgt[9], den = 0.f;
        #pragma unroll
        for (int n = 0; n < 9; ++n) { wgt[n] = __expf(sc[n] - m); den += wgt[n]; }
        const float inv = 1.f / den;
        #pragma unroll
        for (int n = 0; n < 9; ++n) wgt[n] *= inv * valid[n];

        float a[32];
        #pragma unroll
        for (int d = 0; d < 32; ++d) a[d] = 0.f;
        #pragma unroll
        for (int n = 0; n < 9; ++n) {
            const uint4* vp = reinterpret_cast<const uint4*>(
                base + (size_t)offs[n] * 192 + 128 + half * 32);
            const float wn_ = wgt[n];
            #pragma unroll
            for (int c4 = 0; c4 < 4; ++c4) {
                const uint4 t = vp[c4];
                const unsigned wv[4] = {t.x, t.y, t.z, t.w};
                #pragma unroll
                for (int d = 0; d < 4; ++d) {
                    a[c4 * 8 + d * 2 + 0] += wn_ * __uint_as_float(wv[d] << 16);
                    a[c4 * 8 + d * 2 + 1] += wn_ * __uint_as_float(wv[d] & 0xffff0000u);
                }
            }
        }
        #pragma unroll
        for (int c4 = 0; c4 < 4; ++c4) {
            uint4 st;
            st.x = pack2(a[c4 * 8 + 0], a[c4 * 8 + 1]);
            st.y = pack2(a[c4 * 8 + 2], a[c4 * 8 + 3]);
            st.z = pack2(a[c4 * 8 + 4], a[c4 * 8 + 5]);
            st.w = pack2(a[c4 * 8 + 6], a[c4 * 8 + 7]);
            *reinterpret_cast<uint4*>(
                &y_lds[pxl][hi * 64 + half * 32 + c4 * 8]) = st;
        }
    }
    __syncthreads();

    // ---- Proj phase: wave w -> out channels w*64..w*64+63 for the 32 px.
    const int ln15 = lane & 15, grp = lane >> 4;

    f32x4 acc[4][2];
    #pragma unroll
    for (int m = 0; m < 4; ++m)
        #pragma unroll
        for (int n = 0; n < 2; ++n)
            acc[m][n] = (f32x4){0.f, 0.f, 0.f, 0.f};

    #pragma unroll
    for (int ks = 0; ks < 8; ++ks) {      // K = 256, 32 per step
        bf16x8 bfr[2];
        #pragma unroll
        for (int n = 0; n < 2; ++n) {
            const int px = n * 16 + ln15;
            bfr[n] = *reinterpret_cast<const bf16x8*>(
                &y_lds[px][(ks * 4 + grp) * 8]);
        }
        bf16x8 af[4];
        #pragma unroll
        for (int m = 0; m < 4; ++m) {
            const int row = w * 64 + m * 16 + ln15;
            af[m] = *reinterpret_cast<const bf16x8*>(
                WP + (size_t)row * 256 + ks * 32 + grp * 8);
        }
        #pragma unroll
        for (int m = 0; m < 4; ++m)
            #pragma unroll
            for (int n = 0; n < 2; ++n)
                acc[m][n] = __builtin_amdgcn_mfma_f32_16x16x32_bf16(
                    af[m], bfr[n], acc[m][n], 0, 0, 0);
    }

    // Store YP + BN partials.
    u16* Yz = YP + (size_t)batch * CCH * HWSZ;
    float sums[4][4], sqs[4][4];
    #pragma unroll
    for (int m = 0; m < 4; ++m) {
        const int row = w * 64 + m * 16 + grp * 4;
        #pragma unroll
        for (int j = 0; j < 4; ++j) {
            const float v0 = acc[m][0][j], v1 = acc[m][1][j];
            sums[m][j] = v0 + v1;
            sqs[m][j]  = v0 * v0 + v1 * v1;
        }
        #pragma unroll
        for (int n = 0; n < 2; ++n) {
            const int pc = bx * 32 + n * 16 + ln15;
            #pragma unroll
            for (int j = 0; j < 4; ++j)
                Yz[(size_t)(row + j) * PDIM + pc] = f2bf(acc[m][n][j]);
        }
    }
    #pragma unroll
    for (int mask = 1; mask <= 8; mask <<= 1)
        #pragma unroll
        for (int m = 0; m < 4; ++m)
            #pragma unroll
            for (int j = 0; j < 4; ++j) {
                sums[m][j] += __shfl_xor(sums[m][j], mask);
                sqs[m][j]  += __shfl_xor(sqs[m][j],  mask);
            }
    if (ln15 == 0) {
        const int blk = batch * 512 + bx;          // 2048 32-px blocks total
        #pragma unroll
        for (int m = 0; m < 4; ++m) {
            const int row = w * 64 + m * 16 + grp * 4;
            #pragma unroll
            for (int j = 0; j < 4; ++j) {
                const size_t idx = ((size_t)(row + j) * 2048 + blk) * 2;
                part[idx]     = sums[m][j];
                part[idx + 1] = sqs[m][j];
            }
        }
    }
}

// ---------------------------------------------------------------------------
// BN final: per channel, reduce 2048 (sum,sumsq) partials. Deterministic.
// ---------------------------------------------------------------------------
__global__ __launch_bounds__(256) void bn_final(
    const float* __restrict__ part, float* __restrict__ stats)
{
    const int c = blockIdx.x;
    const int tid = threadIdx.x;
    float s = 0.f, q = 0.f;
    #pragma unroll
    for (int it = 0; it < 8; ++it) {
        const int i = tid + it * 256;
        s += part[((size_t)c * 2048 + i) * 2 + 0];
        q += part[((size_t)c * 2048 + i) * 2 + 1];
    }
    __shared__ float sh0[256], sh1[256];
    sh0[tid] = s; sh1[tid] = q;
    __syncthreads();
    for (int st = 128; st > 0; st >>= 1) {
        if (tid < st) { sh0[tid] += sh0[tid + st]; sh1[tid] += sh1[tid + st]; }
        __syncthreads();
    }
    if (tid == 0) {
        const float N = (float)(BATCH * HWSZ);
        const float mean = sh0[0] / N;
        const float var  = sh1[0] / N - mean * mean;
        stats[c]       = mean;
        stats[CCH + c] = rsqrtf(var + 1e-5f);
    }
}

// ---------------------------------------------------------------------------
// Epilogue: out = x + silu( (yp - mean) * invstd * gamma + beta ), yp bf16.
// ---------------------------------------------------------------------------
__global__ __launch_bounds__(256) void bn_silu_res(
    const u16* __restrict__ yp, const float* __restrict__ x,
    const float* __restrict__ stats, const float* __restrict__ gamma,
    const float* __restrict__ beta, float* __restrict__ out)
{
    const size_t i = ((size_t)blockIdx.x * 256 + threadIdx.x) * 8;
    const int c = (int)((i >> 14) & 255);
    const float mean = stats[c];
    const float inv  = stats[CCH + c];
    const float g = gamma[c], bt = beta[c];

    const uint4 yv = *reinterpret_cast<const uint4*>(&yp[i]);
    const unsigned wv[4] = {yv.x, yv.y, yv.z, yv.w};
    float vo[8];
    #pragma unroll
    for (int d = 0; d < 4; ++d) {
        const float y0 = __uint_as_float(wv[d] << 16);
        const float y1 = __uint_as_float(wv[d] & 0xffff0000u);
        const float yn0 = (y0 - mean) * inv * g + bt;
        const float yn1 = (y1 - mean) * inv * g + bt;
        vo[d * 2 + 0] = yn0 / (1.f + __expf(-yn0));
        vo[d * 2 + 1] = yn1 / (1.f + __expf(-yn1));
    }
    const float4 x0 = *reinterpret_cast<const float4*>(&x[i]);
    const float4 x1 = *reinterpret_cast<const float4*>(&x[i + 4]);
    float4 o0, o1;
    o0.x = x0.x + vo[0]; o0.y = x0.y + vo[1];
    o0.z = x0.z + vo[2]; o0.w = x0.w + vo[3];
    o1.x = x1.x + vo[4]; o1.y = x1.y + vo[5];
    o1.z = x1.z + vo[6]; o1.w = x1.w + vo[7];
    *reinterpret_cast<float4*>(&out[i])     = o0;
    *reinterpret_cast<float4*>(&out[i + 4]) = o1;
}

// ---------------------------------------------------------------------------
extern "C" void kernel_launch(void* const* d_in, const int* in_sizes, int n_in,
                              void* d_out, int out_size, void* d_ws, size_t ws_size,
                              hipStream_t stream)
{
    const float* x      = (const float*)d_in[0];
    const float* w_qkv  = (const float*)d_in[1];
    const float* w_proj = (const float*)d_in[2];
    const float* gamma  = (const float*)d_in[3];
    const float* beta   = (const float*)d_in[4];
    float* out = (float*)d_out;

    // ws layout (~88 MB; proven ws >= 134.2 MB):
    //   XT [4][16384][256] bf16 (33.5 MB); YP aliases it (per-pair halves of
    //   XT are dead once that pair's gemm_qkv has consumed them).
    u16*   XT    = (u16*)d_ws;
    u16*   YP    = XT;                               // alias (see above)
    u16*   WQb   = XT + (size_t)BATCH * HWSZ * CCH;  // [768][256]
    u16*   WPb   = WQb + 768 * CCH;                  // [256][256]
    float* part  = (float*)(WPb + CCH * CCH);        // [256][2048][2] = 4 MB
    float* stats = part + (size_t)CCH * 2048 * 2;    // [512]
    u16*   QKVH2 = (u16*)(stats + 512);              // [2*4 heads][16384][192]

    // 1) weights -> bf16
    wconv<<<256, 256, 0, stream>>>(w_qkv, w_proj, WQb, WPb);

    // 2) x -> XT (transpose + bf16)
    transpose_x<<<dim3(HWSZ / 32, CCH / 32, BATCH), 256, 0, stream>>>(x, XT);

    // 3) per batch-pair: QKV GEMM -> fused attention+proj(+BN partials)
    for (int pair = 0; pair < 2; ++pair) {
        const u16* Bx = XT + (size_t)pair * 2 * HWSZ * CCH;
        gemm_qkv<<<dim3(PDIM / 128, 768 / 128, 2), 256, 0, stream>>>(
            WQb, Bx, QKVH2, (long long)HWSZ * CCH);

        attn_proj<<<dim3(HWSZ / 32, 1, 2), 256, 0, stream>>>(
            QKVH2, WPb, YP, part, pair * 2);
    }

    // 4) BN stats from fused partials
    bn_final<<<CCH, 256, 0, stream>>>(part, stats);

    // 5) BN + SiLU + residual: out = x + silu(bn(YP))
    bn_silu_res<<<(unsigned)((size_t)BATCH * CCH * HWSZ / 8 / 256), 256, 0, stream>>>(
        YP, x, stats, gamma, beta, out);
}

// Round 11
// 151.521 us; speedup vs baseline: 1.1555x; 1.1555x over previous
//
#include <hip/hip_runtime.h>
#include <hip/hip_bf16.h>

#define BATCH 4
#define CCH   256
#define HH    128
#define WW    128
#define HWSZ  (HH * WW)         // 16384
#define NHEADS 4
#define DHEAD 64
#define KDIM  256
#define PDIM  16384

typedef unsigned short u16;
typedef short bf16x8 __attribute__((ext_vector_type(8)));
typedef float f32x4  __attribute__((ext_vector_type(4)));

__device__ __forceinline__ float bf2f(u16 u) {
    return __uint_as_float(((unsigned)u) << 16);
}
__device__ __forceinline__ u16 f2bf(float f) {
    unsigned u = __float_as_uint(f);
    unsigned r = (u + 0x7fffu + ((u >> 16) & 1u)) >> 16;
    return (u16)r;
}
__device__ __forceinline__ unsigned pack2(float a, float b) {
    return (unsigned)f2bf(a) | ((unsigned)f2bf(b) << 16);
}
__device__ __forceinline__ void gl_lds16(const u16* g, u16* l) {
    __builtin_amdgcn_global_load_lds(
        (const __attribute__((address_space(1))) void*)g,
        (__attribute__((address_space(3))) void*)l, 16, 0, 0);
}

// ---------------------------------------------------------------------------
// Weight fp32 -> bf16 conversion (both weights in one kernel).
// ---------------------------------------------------------------------------
__global__ __launch_bounds__(256) void wconv(
    const float* __restrict__ wq, const float* __restrict__ wp,
    u16* __restrict__ wqb, u16* __restrict__ wpb)
{
    const int i = (blockIdx.x * 256 + threadIdx.x) * 4;   // < 262144
    const float4 v = (i < 196608)
        ? *reinterpret_cast<const float4*>(&wq[i])
        : *reinterpret_cast<const float4*>(&wp[i - 196608]);
    ushort4 o;
    o.x = f2bf(v.x); o.y = f2bf(v.y); o.z = f2bf(v.z); o.w = f2bf(v.w);
    if (i < 196608) *reinterpret_cast<ushort4*>(&wqb[i]) = o;
    else            *reinterpret_cast<ushort4*>(&wpb[i - 196608]) = o;
}

// ---------------------------------------------------------------------------
// Transpose + convert: x [b][c][p] fp32 -> XT [b][p][c] bf16. 32x32 tiles.
// ---------------------------------------------------------------------------
__global__ __launch_bounds__(256) void transpose_x(
    const float* __restrict__ x, u16* __restrict__ XT)
{
    __shared__ float t[32][33];
    const int b  = blockIdx.z;
    const int c0 = blockIdx.y * 32;
    const int p0 = blockIdx.x * 32;
    const int tid = threadIdx.x;

    #pragma unroll
    for (int it = 0; it < 4; ++it) {
        const int r = it * 8 + (tid >> 5);
        const int col = tid & 31;
        t[r][col] = x[((size_t)b * CCH + c0 + r) * HWSZ + p0 + col];
    }
    __syncthreads();
    #pragma unroll
    for (int it = 0; it < 2; ++it) {
        const int prow = it * 16 + (tid >> 4);
        const int cpair = (tid & 15) * 2;
        const float v0 = t[cpair][prow];
        const float v1 = t[cpair + 1][prow];
        ushort2 o; o.x = f2bf(v0); o.y = f2bf(v1);
        *reinterpret_cast<ushort2*>(
            &XT[((size_t)b * HWSZ + p0 + prow) * CCH + c0 + cpair]) = o;
    }
}

// ---------------------------------------------------------------------------
// QKV MFMA GEMM: D[o][p] = sum_k WQ[o][k] * XT[p][k]  (bf16, k-contiguous)
// K=256, BK=64, tile 128x128, 4 waves (2x2), mfma_f32_16x16x32_bf16.
// Epilogue: C-tile -> LDS Ct[2][128][72] (pixel-major, 144B rows) ->
// coalesced 16B stores into QKVH [(z*4+head)][p][q64|k64|v64].
// Store decomposition: c(8 chunks) x sl(2) x px0(16) x 8 passes = full tile.
// ---------------------------------------------------------------------------
__global__ __launch_bounds__(256) void gemm_qkv(
    const u16* __restrict__ A, const u16* __restrict__ B,
    u16* __restrict__ QKVH, long long b_zs)
{
    constexpr int BK = 64;
    constexpr int CTP = 72;               // Ct row stride (u16): 144B, 16B mult
    __shared__ __align__(16) u16 lds[18432];  // 36864 B union
    u16* As = lds;                        // 8192 u16
    u16* Bs = lds + 8192;                 // 8192 u16

    const int tid  = threadIdx.x;
    const int lane = tid & 63;
    const int w    = tid >> 6;
    const int wm   = w >> 1, wn = w & 1;
    const int o0   = blockIdx.y * 128;
    const int p0   = blockIdx.x * 128;
    const int z    = blockIdx.z;
    const u16* Bz  = B + (size_t)z * b_zs;

    const int srow  = lane >> 3;
    const int sslot = (lane & 7) ^ srow;

    auto stage = [&](int c0) {
        #pragma unroll
        for (int j = 0; j < 4; ++j) {
            const int q = w * 4 + j;
            const int r = q * 8 + srow;
            gl_lds16(A  + (size_t)(o0 + r) * KDIM + c0 + sslot * 8, As + q * 512);
            gl_lds16(Bz + (size_t)(p0 + r) * KDIM + c0 + sslot * 8, Bs + q * 512);
        }
    };

    f32x4 acc[4][4];
    #pragma unroll
    for (int m = 0; m < 4; ++m)
        #pragma unroll
        for (int n = 0; n < 4; ++n)
            acc[m][n] = (f32x4){0.f, 0.f, 0.f, 0.f};

    stage(0);
    #pragma unroll
    for (int kt = 0; kt < KDIM / BK; ++kt) {
        __syncthreads();
        #pragma unroll
        for (int h = 0; h < 2; ++h) {
            bf16x8 af[4], bfr[4];
            #pragma unroll
            for (int m = 0; m < 4; ++m) {
                const int r  = wm * 64 + m * 16 + (lane & 15);
                const int sl = ((h << 2) | (lane >> 4)) ^ (r & 7);
                af[m] = *reinterpret_cast<const bf16x8*>(As + r * BK + sl * 8);
            }
            #pragma unroll
            for (int n = 0; n < 4; ++n) {
                const int r  = wn * 64 + n * 16 + (lane & 15);
                const int sl = ((h << 2) | (lane >> 4)) ^ (r & 7);
                bfr[n] = *reinterpret_cast<const bf16x8*>(Bs + r * BK + sl * 8);
            }
            #pragma unroll
            for (int m = 0; m < 4; ++m)
                #pragma unroll
                for (int n = 0; n < 4; ++n)
                    acc[m][n] = __builtin_amdgcn_mfma_f32_16x16x32_bf16(
                        af[m], bfr[n], acc[m][n], 0, 0, 0);
        }
        if (kt + 1 < KDIM / BK) {
            __syncthreads();
            stage((kt + 1) * BK);
        }
    }

    // Epilogue: acc -> LDS Ct[2][128][CTP] u16 (slice = wm), pixel-major.
    __syncthreads();                      // all LDS reads done, safe to reuse
    u16* Ct = lds;                        // 2*128*72*2 = 36864 B
    const int g = lane >> 4, ln15 = lane & 15;
    #pragma unroll
    for (int m = 0; m < 4; ++m) {
        const int och = m * 16 + g * 4;   // within-slice channel (j packed)
        #pragma unroll
        for (int n = 0; n < 4; ++n) {
            const int px = wn * 64 + n * 16 + ln15;
            uint2 w2;
            w2.x = pack2(acc[m][n][0], acc[m][n][1]);
            w2.y = pack2(acc[m][n][2], acc[m][n][3]);
            *reinterpret_cast<uint2*>(&Ct[(wm * 128 + px) * CTP + och]) = w2;
        }
    }
    __syncthreads();

    // Coalesced store: full coverage 2 slices x 128 px x 8 chunks.
    const int c   = tid & 7;              // 16B chunk within 64-ch slice
    const int sl  = (tid >> 3) & 1;       // slice (o0 + sl*64)
    const int px0 = tid >> 4;             // 0..15
    const int abs_slice = blockIdx.y * 2 + sl;   // 0..11
    const int qkv  = abs_slice >> 2;
    const int head = abs_slice & 3;
    u16* dbase = QKVH + ((size_t)(z * NHEADS + head) * HWSZ) * 192 + qkv * 64 + c * 8;
    #pragma unroll
    for (int pass = 0; pass < 8; ++pass) {
        const int px = px0 + pass * 16;
        const uint4 val = *reinterpret_cast<const uint4*>(
            &Ct[(sl * 128 + px) * CTP + c * 8]);
        *reinterpret_cast<uint4*>(dbase + (size_t)(p0 + px) * 192) = val;
    }
}

// ---------------------------------------------------------------------------
// Dilated neighborhood attention on QKVH [(z*4+head)][p][q64|k64|v64] bf16.
// 4 threads per position (16 channels each); scores combined via
// __shfl_xor(.,1) and (.,2); softmax redundant per quad; PV per 16 channels.
// XCD-aware blockIdx.x swizzle: each XCD gets a contiguous 2048-px band.
// Rate r = hi+1. OOB: score exactly 0 in softmax, zero v contribution.
// ---------------------------------------------------------------------------
__global__ __launch_bounds__(256) void attn4(
    const u16* __restrict__ QKVH, u16* __restrict__ YT)
{
    const int hi  = blockIdx.y;
    const int tid = threadIdx.x;
    const int bxr = blockIdx.x;                       // 0..255
    const int bx  = (bxr & 7) * 32 + (bxr >> 3);      // XCD-contiguous bands
    const int p   = bx * 64 + (tid >> 2);
    const int quarter = tid & 3;
    const int yy = p >> 7;
    const int xx = p & 127;
    const int r  = hi + 1;

    const u16* base = QKVH +
        ((size_t)(blockIdx.z * NHEADS + hi) * HWSZ) * 192;

    // q quarter (16 channels) -> fp32 regs
    const uint4* qp = reinterpret_cast<const uint4*>(
        base + (size_t)p * 192 + quarter * 16);
    float qf[16];
    #pragma unroll
    for (int c4 = 0; c4 < 2; ++c4) {
        const uint4 t = qp[c4];
        const unsigned wv[4] = {t.x, t.y, t.z, t.w};
        #pragma unroll
        for (int d = 0; d < 4; ++d) {
            qf[c4 * 8 + d * 2 + 0] = __uint_as_float(wv[d] << 16);
            qf[c4 * 8 + d * 2 + 1] = __uint_as_float(wv[d] & 0xffff0000u);
        }
    }

    int   offs[9];
    float valid[9];
    #pragma unroll
    for (int n = 0; n < 9; ++n) {
        const int dy = (n / 3 - 1) * r;
        const int dx = (n % 3 - 1) * r;
        const int y2 = yy + dy, x2 = xx + dx;
        const bool ok = (y2 >= 0) && (y2 < HH) && (x2 >= 0) && (x2 < WW);
        valid[n] = ok ? 1.f : 0.f;
        const int y2c = min(max(y2, 0), HH - 1);
        const int x2c = min(max(x2, 0), WW - 1);
        offs[n] = y2c * WW + x2c;
    }

    // Quarter dot-products, then quad-combine
    float sc[9];
    #pragma unroll
    for (int n = 0; n < 9; ++n) {
        const uint4* kp = reinterpret_cast<const uint4*>(
            base + (size_t)offs[n] * 192 + 64 + quarter * 16);
        float s = 0.f;
        #pragma unroll
        for (int c4 = 0; c4 < 2; ++c4) {
            const uint4 t = kp[c4];
            const unsigned wv[4] = {t.x, t.y, t.z, t.w};
            #pragma unroll
            for (int d = 0; d < 4; ++d) {
                s += qf[c4 * 8 + d * 2 + 0] * __uint_as_float(wv[d] << 16);
                s += qf[c4 * 8 + d * 2 + 1] * __uint_as_float(wv[d] & 0xffff0000u);
            }
        }
        sc[n] = s;
    }
    #pragma unroll
    for (int n = 0; n < 9; ++n) {
        sc[n] += __shfl_xor(sc[n], 1);
        sc[n] += __shfl_xor(sc[n], 2);
        sc[n] *= valid[n];
    }

    float m = sc[0];
    #pragma unroll
    for (int n = 1; n < 9; ++n) m = fmaxf(m, sc[n]);
    float wgt[9], den = 0.f;
    #pragma unroll
    for (int n = 0; n < 9; ++n) { wgt[n] = __expf(sc[n] - m); den += wgt[n]; }
    const float inv = 1.f / den;
    #pragma unroll
    for (int n = 0; n < 9; ++n) wgt[n] *= inv * valid[n];

    // PV for this thread's 16 channels
    float a[16];
    #pragma unroll
    for (int d = 0; d < 16; ++d) a[d] = 0.f;
    #pragma unroll
    for (int n = 0; n < 9; ++n) {
        const uint4* vp = reinterpret_cast<const uint4*>(
            base + (size_t)offs[n] * 192 + 128 + quarter * 16);
        const float wn_ = wgt[n];
        #pragma unroll
        for (int c4 = 0; c4 < 2; ++c4) {
            const uint4 t = vp[c4];
            const unsigned wv[4] = {t.x, t.y, t.z, t.w};
            #pragma unroll
            for (int d = 0; d < 4; ++d) {
                a[c4 * 8 + d * 2 + 0] += wn_ * __uint_as_float(wv[d] << 16);
                a[c4 * 8 + d * 2 + 1] += wn_ * __uint_as_float(wv[d] & 0xffff0000u);
            }
        }
    }

    u16* outp = YT + ((size_t)blockIdx.z * HWSZ + p) * CCH
                   + hi * DHEAD + quarter * 16;
    #pragma unroll
    for (int c4 = 0; c4 < 2; ++c4) {
        uint4 st;
        st.x = pack2(a[c4 * 8 + 0], a[c4 * 8 + 1]);
        st.y = pack2(a[c4 * 8 + 2], a[c4 * 8 + 3]);
        st.z = pack2(a[c4 * 8 + 4], a[c4 * 8 + 5]);
        st.w = pack2(a[c4 * 8 + 6], a[c4 * 8 + 7]);
        *reinterpret_cast<uint4*>(outp + c4 * 8) = st;
    }
}

// ---------------------------------------------------------------------------
// Proj MFMA GEMM + fused BN partials: D[o][p] = sum_k WP[o][k] * YT[p][k].
// Writes YP bf16 [batch][o][p] and per-(channel, 64px-block) (sum,sumsq).
// ---------------------------------------------------------------------------
__global__ __launch_bounds__(256) void gemm_proj(
    const u16* __restrict__ A, const u16* __restrict__ B,
    u16* __restrict__ YP, long long b_zs,
    float* __restrict__ part, int batch0)
{
    constexpr int BK = 64;
    __shared__ u16 As[128 * BK];
    __shared__ u16 Bs[128 * BK];

    const int tid  = threadIdx.x;
    const int lane = tid & 63;
    const int w    = tid >> 6;
    const int wm   = w >> 1, wn = w & 1;
    const int o0   = blockIdx.y * 128;
    const int p0   = blockIdx.x * 128;
    const u16* Bz  = B + (size_t)blockIdx.z * b_zs;

    const int srow  = lane >> 3;
    const int sslot = (lane & 7) ^ srow;

    auto stage = [&](int c0) {
        #pragma unroll
        for (int j = 0; j < 4; ++j) {
            const int q = w * 4 + j;
            const int r = q * 8 + srow;
            gl_lds16(A  + (size_t)(o0 + r) * KDIM + c0 + sslot * 8, As + q * 512);
            gl_lds16(Bz + (size_t)(p0 + r) * KDIM + c0 + sslot * 8, Bs + q * 512);
        }
    };

    f32x4 acc[4][4];
    #pragma unroll
    for (int m = 0; m < 4; ++m)
        #pragma unroll
        for (int n = 0; n < 4; ++n)
            acc[m][n] = (f32x4){0.f, 0.f, 0.f, 0.f};

    stage(0);
    #pragma unroll
    for (int kt = 0; kt < KDIM / BK; ++kt) {
        __syncthreads();
        #pragma unroll
        for (int h = 0; h < 2; ++h) {
            bf16x8 af[4], bfr[4];
            #pragma unroll
            for (int m = 0; m < 4; ++m) {
                const int r  = wm * 64 + m * 16 + (lane & 15);
                const int sl = ((h << 2) | (lane >> 4)) ^ (r & 7);
                af[m] = *reinterpret_cast<const bf16x8*>(As + r * BK + sl * 8);
            }
            #pragma unroll
            for (int n = 0; n < 4; ++n) {
                const int r  = wn * 64 + n * 16 + (lane & 15);
                const int sl = ((h << 2) | (lane >> 4)) ^ (r & 7);
                bfr[n] = *reinterpret_cast<const bf16x8*>(Bs + r * BK + sl * 8);
            }
            #pragma unroll
            for (int m = 0; m < 4; ++m)
                #pragma unroll
                for (int n = 0; n < 4; ++n)
                    acc[m][n] = __builtin_amdgcn_mfma_f32_16x16x32_bf16(
                        af[m], bfr[n], acc[m][n], 0, 0, 0);
        }
        if (kt + 1 < KDIM / BK) {
            __syncthreads();
            stage((kt + 1) * BK);
        }
    }

    const int g = lane >> 4, ln15 = lane & 15;
    const int batch = batch0 + blockIdx.z;
    u16* Yz = YP + (size_t)batch * CCH * HWSZ;
    float s[4][4], q2[4][4];
    #pragma unroll
    for (int m = 0; m < 4; ++m) {
        const int ow = o0 + wm * 64 + m * 16 + g * 4;
        #pragma unroll
        for (int j = 0; j < 4; ++j) { s[m][j] = 0.f; q2[m][j] = 0.f; }
        #pragma unroll
        for (int n = 0; n < 4; ++n) {
            const int pc = p0 + wn * 64 + n * 16 + ln15;
            #pragma unroll
            for (int j = 0; j < 4; ++j) {
                const float v = acc[m][n][j];
                Yz[(size_t)(ow + j) * PDIM + pc] = f2bf(v);
                s[m][j]  += v;
                q2[m][j] += v * v;
            }
        }
    }
    // reduce over the 16 px-lanes (bits 0..3 of lane)
    #pragma unroll
    for (int mask = 1; mask <= 8; mask <<= 1) {
        #pragma unroll
        for (int m = 0; m < 4; ++m)
            #pragma unroll
            for (int j = 0; j < 4; ++j) {
                s[m][j]  += __shfl_xor(s[m][j],  mask);
                q2[m][j] += __shfl_xor(q2[m][j], mask);
            }
    }
    if (ln15 == 0) {
        const int pxblk = batch * 256 + blockIdx.x * 2 + wn;  // 64-px block
        #pragma unroll
        for (int m = 0; m < 4; ++m) {
            const int ow = o0 + wm * 64 + m * 16 + g * 4;
            #pragma unroll
            for (int j = 0; j < 4; ++j) {
                const size_t idx = ((size_t)(ow + j) * 1024 + pxblk) * 2;
                part[idx]     = s[m][j];
                part[idx + 1] = q2[m][j];
            }
        }
    }
}

// ---------------------------------------------------------------------------
// BN final: per channel, reduce 1024 (sum,sumsq) partials. Deterministic.
// ---------------------------------------------------------------------------
__global__ __launch_bounds__(256) void bn_final(
    const float* __restrict__ part, float* __restrict__ stats)
{
    const int c = blockIdx.x;
    const int tid = threadIdx.x;
    float s = 0.f, q = 0.f;
    #pragma unroll
    for (int it = 0; it < 4; ++it) {
        const int i = tid + it * 256;
        s += part[((size_t)c * 1024 + i) * 2 + 0];
        q += part[((size_t)c * 1024 + i) * 2 + 1];
    }
    __shared__ float sh0[256], sh1[256];
    sh0[tid] = s; sh1[tid] = q;
    __syncthreads();
    for (int st = 128; st > 0; st >>= 1) {
        if (tid < st) { sh0[tid] += sh0[tid + st]; sh1[tid] += sh1[tid + st]; }
        __syncthreads();
    }
    if (tid == 0) {
        const float N = (float)(BATCH * HWSZ);
        const float mean = sh0[0] / N;
        const float var  = sh1[0] / N - mean * mean;
        stats[c]       = mean;
        stats[CCH + c] = rsqrtf(var + 1e-5f);
    }
}

// ---------------------------------------------------------------------------
// Epilogue: out = x + silu( (yp - mean) * invstd * gamma + beta ), yp bf16.
// ---------------------------------------------------------------------------
__global__ __launch_bounds__(256) void bn_silu_res(
    const u16* __restrict__ yp, const float* __restrict__ x,
    const float* __restrict__ stats, const float* __restrict__ gamma,
    const float* __restrict__ beta, float* __restrict__ out)
{
    const size_t i = ((size_t)blockIdx.x * 256 + threadIdx.x) * 8;
    const int c = (int)((i >> 14) & 255);
    const float mean = stats[c];
    const float inv  = stats[CCH + c];
    const float g = gamma[c], bt = beta[c];

    const uint4 yv = *reinterpret_cast<const uint4*>(&yp[i]);
    const unsigned wv[4] = {yv.x, yv.y, yv.z, yv.w};
    float vo[8];
    #pragma unroll
    for (int d = 0; d < 4; ++d) {
        const float y0 = __uint_as_float(wv[d] << 16);
        const float y1 = __uint_as_float(wv[d] & 0xffff0000u);
        const float yn0 = (y0 - mean) * inv * g + bt;
        const float yn1 = (y1 - mean) * inv * g + bt;
        vo[d * 2 + 0] = yn0 / (1.f + __expf(-yn0));
        vo[d * 2 + 1] = yn1 / (1.f + __expf(-yn1));
    }
    const float4 x0 = *reinterpret_cast<const float4*>(&x[i]);
    const float4 x1 = *reinterpret_cast<const float4*>(&x[i + 4]);
    float4 o0, o1;
    o0.x = x0.x + vo[0]; o0.y = x0.y + vo[1];
    o0.z = x0.z + vo[2]; o0.w = x0.w + vo[3];
    o1.x = x1.x + vo[4]; o1.y = x1.y + vo[5];
    o1.z = x1.z + vo[6]; o1.w = x1.w + vo[7];
    *reinterpret_cast<float4*>(&out[i])     = o0;
    *reinterpret_cast<float4*>(&out[i + 4]) = o1;
}

// ---------------------------------------------------------------------------
extern "C" void kernel_launch(void* const* d_in, const int* in_sizes, int n_in,
                              void* d_out, int out_size, void* d_ws, size_t ws_size,
                              hipStream_t stream)
{
    const float* x      = (const float*)d_in[0];
    const float* w_qkv  = (const float*)d_in[1];
    const float* w_proj = (const float*)d_in[2];
    const float* gamma  = (const float*)d_in[3];
    const float* beta   = (const float*)d_in[4];
    float* out = (float*)d_out;

    // ws layout (~103 MB; proven ws >= 134.2 MB):
    //   XT [4][16384][256] bf16 (33.5 MB); YP aliases it (per-pair halves of
    //   XT are dead once that pair's gemm_qkv has consumed them).
    u16*   XT    = (u16*)d_ws;
    u16*   YP    = XT;                               // alias (see above)
    u16*   WQb   = XT + (size_t)BATCH * HWSZ * CCH;  // [768][256]
    u16*   WPb   = WQb + 768 * CCH;                  // [256][256]
    float* part  = (float*)(WPb + CCH * CCH);        // [256][1024][2] = 2 MB
    float* stats = part + (size_t)CCH * 1024 * 2;    // [512]
    u16*   QKVH2 = (u16*)(stats + 512);              // [2*4 heads][16384][192]
    u16*   YT2   = QKVH2 + (size_t)2 * HWSZ * 768;   // [2][16384][256]

    // 1) weights -> bf16
    wconv<<<256, 256, 0, stream>>>(w_qkv, w_proj, WQb, WPb);

    // 2) x -> XT (transpose + bf16)
    transpose_x<<<dim3(HWSZ / 32, CCH / 32, BATCH), 256, 0, stream>>>(x, XT);

    // 3) per batch-pair: QKV GEMM -> attention -> proj GEMM (+BN partials)
    for (int pair = 0; pair < 2; ++pair) {
        const u16* Bx = XT + (size_t)pair * 2 * HWSZ * CCH;
        gemm_qkv<<<dim3(PDIM / 128, 768 / 128, 2), 256, 0, stream>>>(
            WQb, Bx, QKVH2, (long long)HWSZ * CCH);

        attn4<<<dim3(HWSZ / 64, NHEADS, 2), 256, 0, stream>>>(QKVH2, YT2);

        gemm_proj<<<dim3(PDIM / 128, CCH / 128, 2), 256, 0, stream>>>(
            WPb, YT2, YP, (long long)HWSZ * CCH, part, pair * 2);
    }

    // 4) BN stats from fused partials
    bn_final<<<CCH, 256, 0, stream>>>(part, stats);

    // 5) BN + SiLU + residual: out = x + silu(bn(YP))
    bn_silu_res<<<(unsigned)((size_t)BATCH * CCH * HWSZ / 8 / 256), 256, 0, stream>>>(
        YP, x, stats, gamma, beta, out);
}

// Round 12
// 143.987 us; speedup vs baseline: 1.2160x; 1.0523x over previous
//
#include <hip/hip_runtime.h>
#include <hip/hip_bf16.h>

#define BATCH 4
#define CCH   256
#define HH    128
#define WW    128
#define HWSZ  (HH * WW)         // 16384
#define NHEADS 4
#define DHEAD 64
#define KDIM  256
#define PDIM  16384

typedef unsigned short u16;
typedef short bf16x8 __attribute__((ext_vector_type(8)));
typedef float f32x4  __attribute__((ext_vector_type(4)));

__device__ __forceinline__ float bf2f(u16 u) {
    return __uint_as_float(((unsigned)u) << 16);
}
__device__ __forceinline__ u16 f2bf(float f) {
    unsigned u = __float_as_uint(f);
    unsigned r = (u + 0x7fffu + ((u >> 16) & 1u)) >> 16;
    return (u16)r;
}
__device__ __forceinline__ unsigned pack2(float a, float b) {
    return (unsigned)f2bf(a) | ((unsigned)f2bf(b) << 16);
}
__device__ __forceinline__ void gl_lds16(const u16* g, u16* l) {
    __builtin_amdgcn_global_load_lds(
        (const __attribute__((address_space(1))) void*)g,
        (__attribute__((address_space(3))) void*)l, 16, 0, 0);
}

// ---------------------------------------------------------------------------
// Weight fp32 -> bf16 conversion (both weights in one kernel).
// ---------------------------------------------------------------------------
__global__ __launch_bounds__(256) void wconv(
    const float* __restrict__ wq, const float* __restrict__ wp,
    u16* __restrict__ wqb, u16* __restrict__ wpb)
{
    const int i = (blockIdx.x * 256 + threadIdx.x) * 4;   // < 262144
    const float4 v = (i < 196608)
        ? *reinterpret_cast<const float4*>(&wq[i])
        : *reinterpret_cast<const float4*>(&wp[i - 196608]);
    ushort4 o;
    o.x = f2bf(v.x); o.y = f2bf(v.y); o.z = f2bf(v.z); o.w = f2bf(v.w);
    if (i < 196608) *reinterpret_cast<ushort4*>(&wqb[i]) = o;
    else            *reinterpret_cast<ushort4*>(&wpb[i - 196608]) = o;
}

// ---------------------------------------------------------------------------
// Transpose + convert: x [b][c][p] fp32 -> XT [b][p][c] bf16. 32x32 tiles.
// ---------------------------------------------------------------------------
__global__ __launch_bounds__(256) void transpose_x(
    const float* __restrict__ x, u16* __restrict__ XT)
{
    __shared__ float t[32][33];
    const int b  = blockIdx.z;
    const int c0 = blockIdx.y * 32;
    const int p0 = blockIdx.x * 32;
    const int tid = threadIdx.x;

    #pragma unroll
    for (int it = 0; it < 4; ++it) {
        const int r = it * 8 + (tid >> 5);
        const int col = tid & 31;
        t[r][col] = x[((size_t)b * CCH + c0 + r) * HWSZ + p0 + col];
    }
    __syncthreads();
    #pragma unroll
    for (int it = 0; it < 2; ++it) {
        const int prow = it * 16 + (tid >> 4);
        const int cpair = (tid & 15) * 2;
        const float v0 = t[cpair][prow];
        const float v1 = t[cpair + 1][prow];
        ushort2 o; o.x = f2bf(v0); o.y = f2bf(v1);
        *reinterpret_cast<ushort2*>(
            &XT[((size_t)b * HWSZ + p0 + prow) * CCH + c0 + cpair]) = o;
    }
}

// ---------------------------------------------------------------------------
// QKV MFMA GEMM: D[o][p] = sum_k WQ[o][k] * XT[p][k]  (bf16, k-contiguous)
// K=256, BK=64, tile 128x128, 4 waves (2x2), mfma_f32_16x16x32_bf16.
// Epilogue: C-tile -> LDS Ct[2][128][72] (pixel-major, 144B rows) ->
// coalesced 16B stores into QKVH [(z*4+head)][p][q64|k64|v64].
// ---------------------------------------------------------------------------
__global__ __launch_bounds__(256) void gemm_qkv(
    const u16* __restrict__ A, const u16* __restrict__ B,
    u16* __restrict__ QKVH, long long b_zs)
{
    constexpr int BK = 64;
    constexpr int CTP = 72;               // Ct row stride (u16): 144B, 16B mult
    __shared__ __align__(16) u16 lds[18432];  // 36864 B union
    u16* As = lds;                        // 8192 u16
    u16* Bs = lds + 8192;                 // 8192 u16

    const int tid  = threadIdx.x;
    const int lane = tid & 63;
    const int w    = tid >> 6;
    const int wm   = w >> 1, wn = w & 1;
    const int o0   = blockIdx.y * 128;
    const int p0   = blockIdx.x * 128;
    const int z    = blockIdx.z;
    const u16* Bz  = B + (size_t)z * b_zs;

    const int srow  = lane >> 3;
    const int sslot = (lane & 7) ^ srow;

    auto stage = [&](int c0) {
        #pragma unroll
        for (int j = 0; j < 4; ++j) {
            const int q = w * 4 + j;
            const int r = q * 8 + srow;
            gl_lds16(A  + (size_t)(o0 + r) * KDIM + c0 + sslot * 8, As + q * 512);
            gl_lds16(Bz + (size_t)(p0 + r) * KDIM + c0 + sslot * 8, Bs + q * 512);
        }
    };

    f32x4 acc[4][4];
    #pragma unroll
    for (int m = 0; m < 4; ++m)
        #pragma unroll
        for (int n = 0; n < 4; ++n)
            acc[m][n] = (f32x4){0.f, 0.f, 0.f, 0.f};

    stage(0);
    #pragma unroll
    for (int kt = 0; kt < KDIM / BK; ++kt) {
        __syncthreads();
        #pragma unroll
        for (int h = 0; h < 2; ++h) {
            bf16x8 af[4], bfr[4];
            #pragma unroll
            for (int m = 0; m < 4; ++m) {
                const int r  = wm * 64 + m * 16 + (lane & 15);
                const int sl = ((h << 2) | (lane >> 4)) ^ (r & 7);
                af[m] = *reinterpret_cast<const bf16x8*>(As + r * BK + sl * 8);
            }
            #pragma unroll
            for (int n = 0; n < 4; ++n) {
                const int r  = wn * 64 + n * 16 + (lane & 15);
                const int sl = ((h << 2) | (lane >> 4)) ^ (r & 7);
                bfr[n] = *reinterpret_cast<const bf16x8*>(Bs + r * BK + sl * 8);
            }
            #pragma unroll
            for (int m = 0; m < 4; ++m)
                #pragma unroll
                for (int n = 0; n < 4; ++n)
                    acc[m][n] = __builtin_amdgcn_mfma_f32_16x16x32_bf16(
                        af[m], bfr[n], acc[m][n], 0, 0, 0);
        }
        if (kt + 1 < KDIM / BK) {
            __syncthreads();
            stage((kt + 1) * BK);
        }
    }

    // Epilogue: acc -> LDS Ct[2][128][CTP] u16 (slice = wm), pixel-major.
    __syncthreads();                      // all LDS reads done, safe to reuse
    u16* Ct = lds;                        // 2*128*72*2 = 36864 B
    const int g = lane >> 4, ln15 = lane & 15;
    #pragma unroll
    for (int m = 0; m < 4; ++m) {
        const int och = m * 16 + g * 4;   // within-slice channel (j packed)
        #pragma unroll
        for (int n = 0; n < 4; ++n) {
            const int px = wn * 64 + n * 16 + ln15;
            uint2 w2;
            w2.x = pack2(acc[m][n][0], acc[m][n][1]);
            w2.y = pack2(acc[m][n][2], acc[m][n][3]);
            *reinterpret_cast<uint2*>(&Ct[(wm * 128 + px) * CTP + och]) = w2;
        }
    }
    __syncthreads();

    // Coalesced store: full coverage 2 slices x 128 px x 8 chunks.
    const int c   = tid & 7;              // 16B chunk within 64-ch slice
    const int sl  = (tid >> 3) & 1;       // slice (o0 + sl*64)
    const int px0 = tid >> 4;             // 0..15
    const int abs_slice = blockIdx.y * 2 + sl;   // 0..11
    const int qkv  = abs_slice >> 2;
    const int head = abs_slice & 3;
    u16* dbase = QKVH + ((size_t)(z * NHEADS + head) * HWSZ) * 192 + qkv * 64 + c * 8;
    #pragma unroll
    for (int pass = 0; pass < 8; ++pass) {
        const int px = px0 + pass * 16;
        const uint4 val = *reinterpret_cast<const uint4*>(
            &Ct[(sl * 128 + px) * CTP + c * 8]);
        *reinterpret_cast<uint4*>(dbase + (size_t)(p0 + px) * 192) = val;
    }
}

// ---------------------------------------------------------------------------
// Dilated neighborhood attention on QKVH [(z*4+head)][p][q64|k64|v64] bf16.
// 4 threads per position (16 channels each); scores combined via
// __shfl_xor(.,1) and (.,2); softmax redundant per quad; PV per 16 channels.
// XCD-aware blockIdx.x swizzle. OOB: score exactly 0 in softmax, zero v.
// ---------------------------------------------------------------------------
__global__ __launch_bounds__(256) void attn4(
    const u16* __restrict__ QKVH, u16* __restrict__ YT)
{
    const int hi  = blockIdx.y;
    const int tid = threadIdx.x;
    const int bxr = blockIdx.x;                       // 0..255
    const int bx  = (bxr & 7) * 32 + (bxr >> 3);      // XCD-contiguous bands
    const int p   = bx * 64 + (tid >> 2);
    const int quarter = tid & 3;
    const int yy = p >> 7;
    const int xx = p & 127;
    const int r  = hi + 1;

    const u16* base = QKVH +
        ((size_t)(blockIdx.z * NHEADS + hi) * HWSZ) * 192;

    // q quarter (16 channels) -> fp32 regs
    const uint4* qp = reinterpret_cast<const uint4*>(
        base + (size_t)p * 192 + quarter * 16);
    float qf[16];
    #pragma unroll
    for (int c4 = 0; c4 < 2; ++c4) {
        const uint4 t = qp[c4];
        const unsigned wv[4] = {t.x, t.y, t.z, t.w};
        #pragma unroll
        for (int d = 0; d < 4; ++d) {
            qf[c4 * 8 + d * 2 + 0] = __uint_as_float(wv[d] << 16);
            qf[c4 * 8 + d * 2 + 1] = __uint_as_float(wv[d] & 0xffff0000u);
        }
    }

    int   offs[9];
    float valid[9];
    #pragma unroll
    for (int n = 0; n < 9; ++n) {
        const int dy = (n / 3 - 1) * r;
        const int dx = (n % 3 - 1) * r;
        const int y2 = yy + dy, x2 = xx + dx;
        const bool ok = (y2 >= 0) && (y2 < HH) && (x2 >= 0) && (x2 < WW);
        valid[n] = ok ? 1.f : 0.f;
        const int y2c = min(max(y2, 0), HH - 1);
        const int x2c = min(max(x2, 0), WW - 1);
        offs[n] = y2c * WW + x2c;
    }

    // Quarter dot-products, then quad-combine
    float sc[9];
    #pragma unroll
    for (int n = 0; n < 9; ++n) {
        const uint4* kp = reinterpret_cast<const uint4*>(
            base + (size_t)offs[n] * 192 + 64 + quarter * 16);
        float s = 0.f;
        #pragma unroll
        for (int c4 = 0; c4 < 2; ++c4) {
            const uint4 t = kp[c4];
            const unsigned wv[4] = {t.x, t.y, t.z, t.w};
            #pragma unroll
            for (int d = 0; d < 4; ++d) {
                s += qf[c4 * 8 + d * 2 + 0] * __uint_as_float(wv[d] << 16);
                s += qf[c4 * 8 + d * 2 + 1] * __uint_as_float(wv[d] & 0xffff0000u);
            }
        }
        sc[n] = s;
    }
    #pragma unroll
    for (int n = 0; n < 9; ++n) {
        sc[n] += __shfl_xor(sc[n], 1);
        sc[n] += __shfl_xor(sc[n], 2);
        sc[n] *= valid[n];
    }

    float m = sc[0];
    #pragma unroll
    for (int n = 1; n < 9; ++n) m = fmaxf(m, sc[n]);
    float wgt[9], den = 0.f;
    #pragma unroll
    for (int n = 0; n < 9; ++n) { wgt[n] = __expf(sc[n] - m); den += wgt[n]; }
    const float inv = 1.f / den;
    #pragma unroll
    for (int n = 0; n < 9; ++n) wgt[n] *= inv * valid[n];

    // PV for this thread's 16 channels
    float a[16];
    #pragma unroll
    for (int d = 0; d < 16; ++d) a[d] = 0.f;
    #pragma unroll
    for (int n = 0; n < 9; ++n) {
        const uint4* vp = reinterpret_cast<const uint4*>(
            base + (size_t)offs[n] * 192 + 128 + quarter * 16);
        const float wn_ = wgt[n];
        #pragma unroll
        for (int c4 = 0; c4 < 2; ++c4) {
            const uint4 t = vp[c4];
            const unsigned wv[4] = {t.x, t.y, t.z, t.w};
            #pragma unroll
            for (int d = 0; d < 4; ++d) {
                a[c4 * 8 + d * 2 + 0] += wn_ * __uint_as_float(wv[d] << 16);
                a[c4 * 8 + d * 2 + 1] += wn_ * __uint_as_float(wv[d] & 0xffff0000u);
            }
        }
    }

    u16* outp = YT + ((size_t)blockIdx.z * HWSZ + p) * CCH
                   + hi * DHEAD + quarter * 16;
    #pragma unroll
    for (int c4 = 0; c4 < 2; ++c4) {
        uint4 st;
        st.x = pack2(a[c4 * 8 + 0], a[c4 * 8 + 1]);
        st.y = pack2(a[c4 * 8 + 2], a[c4 * 8 + 3]);
        st.z = pack2(a[c4 * 8 + 4], a[c4 * 8 + 5]);
        st.w = pack2(a[c4 * 8 + 6], a[c4 * 8 + 7]);
        *reinterpret_cast<uint4*>(outp + c4 * 8) = st;
    }
}

// ---------------------------------------------------------------------------
// Proj MFMA GEMM + fused BN partials: D[o][p] = sum_k WP[o][k] * YT[p][k].
// Writes YP bf16 [batch][o][p] and per-(channel, 64px-block) (sum,sumsq).
// ---------------------------------------------------------------------------
__global__ __launch_bounds__(256) void gemm_proj(
    const u16* __restrict__ A, const u16* __restrict__ B,
    u16* __restrict__ YP, long long b_zs,
    float* __restrict__ part, int batch0)
{
    constexpr int BK = 64;
    __shared__ u16 As[128 * BK];
    __shared__ u16 Bs[128 * BK];

    const int tid  = threadIdx.x;
    const int lane = tid & 63;
    const int w    = tid >> 6;
    const int wm   = w >> 1, wn = w & 1;
    const int o0   = blockIdx.y * 128;
    const int p0   = blockIdx.x * 128;
    const u16* Bz  = B + (size_t)blockIdx.z * b_zs;

    const int srow  = lane >> 3;
    const int sslot = (lane & 7) ^ srow;

    auto stage = [&](int c0) {
        #pragma unroll
        for (int j = 0; j < 4; ++j) {
            const int q = w * 4 + j;
            const int r = q * 8 + srow;
            gl_lds16(A  + (size_t)(o0 + r) * KDIM + c0 + sslot * 8, As + q * 512);
            gl_lds16(Bz + (size_t)(p0 + r) * KDIM + c0 + sslot * 8, Bs + q * 512);
        }
    };

    f32x4 acc[4][4];
    #pragma unroll
    for (int m = 0; m < 4; ++m)
        #pragma unroll
        for (int n = 0; n < 4; ++n)
            acc[m][n] = (f32x4){0.f, 0.f, 0.f, 0.f};

    stage(0);
    #pragma unroll
    for (int kt = 0; kt < KDIM / BK; ++kt) {
        __syncthreads();
        #pragma unroll
        for (int h = 0; h < 2; ++h) {
            bf16x8 af[4], bfr[4];
            #pragma unroll
            for (int m = 0; m < 4; ++m) {
                const int r  = wm * 64 + m * 16 + (lane & 15);
                const int sl = ((h << 2) | (lane >> 4)) ^ (r & 7);
                af[m] = *reinterpret_cast<const bf16x8*>(As + r * BK + sl * 8);
            }
            #pragma unroll
            for (int n = 0; n < 4; ++n) {
                const int r  = wn * 64 + n * 16 + (lane & 15);
                const int sl = ((h << 2) | (lane >> 4)) ^ (r & 7);
                bfr[n] = *reinterpret_cast<const bf16x8*>(Bs + r * BK + sl * 8);
            }
            #pragma unroll
            for (int m = 0; m < 4; ++m)
                #pragma unroll
                for (int n = 0; n < 4; ++n)
                    acc[m][n] = __builtin_amdgcn_mfma_f32_16x16x32_bf16(
                        af[m], bfr[n], acc[m][n], 0, 0, 0);
        }
        if (kt + 1 < KDIM / BK) {
            __syncthreads();
            stage((kt + 1) * BK);
        }
    }

    const int g = lane >> 4, ln15 = lane & 15;
    const int batch = batch0 + blockIdx.z;
    u16* Yz = YP + (size_t)batch * CCH * HWSZ;
    float s[4][4], q2[4][4];
    #pragma unroll
    for (int m = 0; m < 4; ++m) {
        const int ow = o0 + wm * 64 + m * 16 + g * 4;
        #pragma unroll
        for (int j = 0; j < 4; ++j) { s[m][j] = 0.f; q2[m][j] = 0.f; }
        #pragma unroll
        for (int n = 0; n < 4; ++n) {
            const int pc = p0 + wn * 64 + n * 16 + ln15;
            #pragma unroll
            for (int j = 0; j < 4; ++j) {
                const float v = acc[m][n][j];
                Yz[(size_t)(ow + j) * PDIM + pc] = f2bf(v);
                s[m][j]  += v;
                q2[m][j] += v * v;
            }
        }
    }
    // reduce over the 16 px-lanes (bits 0..3 of lane)
    #pragma unroll
    for (int mask = 1; mask <= 8; mask <<= 1) {
        #pragma unroll
        for (int m = 0; m < 4; ++m)
            #pragma unroll
            for (int j = 0; j < 4; ++j) {
                s[m][j]  += __shfl_xor(s[m][j],  mask);
                q2[m][j] += __shfl_xor(q2[m][j], mask);
            }
    }
    if (ln15 == 0) {
        const int pxblk = batch * 256 + blockIdx.x * 2 + wn;  // 64-px block
        #pragma unroll
        for (int m = 0; m < 4; ++m) {
            const int ow = o0 + wm * 64 + m * 16 + g * 4;
            #pragma unroll
            for (int j = 0; j < 4; ++j) {
                const size_t idx = ((size_t)(ow + j) * 1024 + pxblk) * 2;
                part[idx]     = s[m][j];
                part[idx + 1] = q2[m][j];
            }
        }
    }
}

// ---------------------------------------------------------------------------
// BN final: per channel, reduce 1024 (sum,sumsq) partials. Deterministic.
// ---------------------------------------------------------------------------
__global__ __launch_bounds__(256) void bn_final(
    const float* __restrict__ part, float* __restrict__ stats)
{
    const int c = blockIdx.x;
    const int tid = threadIdx.x;
    float s = 0.f, q = 0.f;
    #pragma unroll
    for (int it = 0; it < 4; ++it) {
        const int i = tid + it * 256;
        s += part[((size_t)c * 1024 + i) * 2 + 0];
        q += part[((size_t)c * 1024 + i) * 2 + 1];
    }
    __shared__ float sh0[256], sh1[256];
    sh0[tid] = s; sh1[tid] = q;
    __syncthreads();
    for (int st = 128; st > 0; st >>= 1) {
        if (tid < st) { sh0[tid] += sh0[tid + st]; sh1[tid] += sh1[tid + st]; }
        __syncthreads();
    }
    if (tid == 0) {
        const float N = (float)(BATCH * HWSZ);
        const float mean = sh0[0] / N;
        const float var  = sh1[0] / N - mean * mean;
        stats[c]       = mean;
        stats[CCH + c] = rsqrtf(var + 1e-5f);
    }
}

// ---------------------------------------------------------------------------
// Epilogue: out = x + silu( (yp - mean) * invstd * gamma + beta ), yp bf16.
// ---------------------------------------------------------------------------
__global__ __launch_bounds__(256) void bn_silu_res(
    const u16* __restrict__ yp, const float* __restrict__ x,
    const float* __restrict__ stats, const float* __restrict__ gamma,
    const float* __restrict__ beta, float* __restrict__ out)
{
    const size_t i = ((size_t)blockIdx.x * 256 + threadIdx.x) * 8;
    const int c = (int)((i >> 14) & 255);
    const float mean = stats[c];
    const float inv  = stats[CCH + c];
    const float g = gamma[c], bt = beta[c];

    const uint4 yv = *reinterpret_cast<const uint4*>(&yp[i]);
    const unsigned wv[4] = {yv.x, yv.y, yv.z, yv.w};
    float vo[8];
    #pragma unroll
    for (int d = 0; d < 4; ++d) {
        const float y0 = __uint_as_float(wv[d] << 16);
        const float y1 = __uint_as_float(wv[d] & 0xffff0000u);
        const float yn0 = (y0 - mean) * inv * g + bt;
        const float yn1 = (y1 - mean) * inv * g + bt;
        vo[d * 2 + 0] = yn0 / (1.f + __expf(-yn0));
        vo[d * 2 + 1] = yn1 / (1.f + __expf(-yn1));
    }
    const float4 x0 = *reinterpret_cast<const float4*>(&x[i]);
    const float4 x1 = *reinterpret_cast<const float4*>(&x[i + 4]);
    float4 o0, o1;
    o0.x = x0.x + vo[0]; o0.y = x0.y + vo[1];
    o0.z = x0.z + vo[2]; o0.w = x0.w + vo[3];
    o1.x = x1.x + vo[4]; o1.y = x1.y + vo[5];
    o1.z = x1.z + vo[6]; o1.w = x1.w + vo[7];
    *reinterpret_cast<float4*>(&out[i])     = o0;
    *reinterpret_cast<float4*>(&out[i + 4]) = o1;
}

// ---------------------------------------------------------------------------
extern "C" void kernel_launch(void* const* d_in, const int* in_sizes, int n_in,
                              void* d_out, int out_size, void* d_ws, size_t ws_size,
                              hipStream_t stream)
{
    const float* x      = (const float*)d_in[0];
    const float* w_qkv  = (const float*)d_in[1];
    const float* w_proj = (const float*)d_in[2];
    const float* gamma  = (const float*)d_in[3];
    const float* beta   = (const float*)d_in[4];
    float* out = (float*)d_out;

    // ws layout:
    //   XT [4][16384][256] bf16 (33.5 MB); YP aliases it (XT is fully dead
    //   once gemm_qkv for those batches has consumed it).
    //   QKVH: [z*4 heads][16384][192]; YT follows QKVH.
    //   Full path (z=4, single pass): 170.4 MB. Pair path (z=2): ~103 MB
    //   (proven; round-3 evidence proves ws >= 134.2 MB).
    u16*   XT    = (u16*)d_ws;
    u16*   YP    = XT;                               // alias (see above)
    u16*   WQb   = XT + (size_t)BATCH * HWSZ * CCH;  // [768][256]
    u16*   WPb   = WQb + 768 * CCH;                  // [256][256]
    float* part  = (float*)(WPb + CCH * CCH);        // [256][1024][2] = 2 MB
    float* stats = part + (size_t)CCH * 1024 * 2;    // [512]
    u16*   QKVH  = (u16*)(stats + 512);

    const size_t qkvh_full = (size_t)BATCH * NHEADS * HWSZ * 192;   // 4 batches
    const size_t yt_full   = (size_t)BATCH * HWSZ * CCH;
    u16* YT_full = QKVH + qkvh_full;
    u16* YT_pair = QKVH + qkvh_full / 2;

    const size_t need_full =
        (size_t)((char*)(YT_full + yt_full) - (char*)d_ws);

    // 1) weights -> bf16
    wconv<<<256, 256, 0, stream>>>(w_qkv, w_proj, WQb, WPb);

    // 2) x -> XT (transpose + bf16)
    transpose_x<<<dim3(HWSZ / 32, CCH / 32, BATCH), 256, 0, stream>>>(x, XT);

    if (ws_size >= need_full) {
        // 3a) Single pass, z = 4: QKV GEMM -> attention -> proj (+BN partials)
        gemm_qkv<<<dim3(PDIM / 128, 768 / 128, BATCH), 256, 0, stream>>>(
            WQb, XT, QKVH, (long long)HWSZ * CCH);

        attn4<<<dim3(HWSZ / 64, NHEADS, BATCH), 256, 0, stream>>>(QKVH, YT_full);

        gemm_proj<<<dim3(PDIM / 128, CCH / 128, BATCH), 256, 0, stream>>>(
            WPb, YT_full, YP, (long long)HWSZ * CCH, part, 0);
    } else {
        // 3b) Two passes of batch pairs (z = 2), QKVH/YT regions reused.
        for (int pair = 0; pair < 2; ++pair) {
            const u16* Bx = XT + (size_t)pair * 2 * HWSZ * CCH;
            gemm_qkv<<<dim3(PDIM / 128, 768 / 128, 2), 256, 0, stream>>>(
                WQb, Bx, QKVH, (long long)HWSZ * CCH);

            attn4<<<dim3(HWSZ / 64, NHEADS, 2), 256, 0, stream>>>(QKVH, YT_pair);

            gemm_proj<<<dim3(PDIM / 128, CCH / 128, 2), 256, 0, stream>>>(
                WPb, YT_pair, YP, (long long)HWSZ * CCH, part, pair * 2);
        }
    }

    // 4) BN stats from fused partials
    bn_final<<<CCH, 256, 0, stream>>>(part, stats);

    // 5) BN + SiLU + residual: out = x + silu(bn(YP))
    bn_silu_res<<<(unsigned)((size_t)BATCH * CCH * HWSZ / 8 / 256), 256, 0, stream>>>(
        YP, x, stats, gamma, beta, out);
}